// Round 1
// baseline (60.841 us; speedup 1.0000x reference)
//
#include <hip/hip_runtime.h>

// DCN cross network: x_{i+1} = x0 * (x_i . w_i) + b_i + x_i, L=4 layers.
// One workgroup (256 threads) per row; row state (x0, cur) lives in registers
// as one float4 per thread. Per layer: block-wide dot product (wave shuffle
// reduce + 4-wave LDS combine), then FMA update. Memory-bound: read x once,
// write out once (~256 MB total).

#define DCN_D 1024
#define DCN_L 4
#define DCN_BLOCK 256   // D / 4 elems-per-thread

__global__ __launch_bounds__(DCN_BLOCK) void dcn_cross_kernel(
    const float* __restrict__ x,
    const float* __restrict__ weights,   // [L, D]
    const float* __restrict__ biases,    // [L, D]
    float* __restrict__ out,             // [B, D]
    int B)
{
    const int row = blockIdx.x;
    if (row >= B) return;
    const int t = threadIdx.x;

    const float4* __restrict__ xrow =
        reinterpret_cast<const float4*>(x + (size_t)row * DCN_D);
    const float4 x0 = xrow[t];
    float4 cur = x0;

    __shared__ float red[DCN_BLOCK / 64];  // one partial per wave (4 waves)

    const int wave = t >> 6;
    const int lane = t & 63;

    #pragma unroll
    for (int l = 0; l < DCN_L; ++l) {
        const float4 w =
            reinterpret_cast<const float4*>(weights + (size_t)l * DCN_D)[t];
        // per-thread partial dot
        float p = cur.x * w.x;
        p = fmaf(cur.y, w.y, p);
        p = fmaf(cur.z, w.z, p);
        p = fmaf(cur.w, w.w, p);
        // 64-lane wave reduction
        #pragma unroll
        for (int off = 32; off > 0; off >>= 1)
            p += __shfl_down(p, off, 64);
        if (lane == 0) red[wave] = p;
        __syncthreads();
        const float s = red[0] + red[1] + red[2] + red[3];

        const float4 b =
            reinterpret_cast<const float4*>(biases + (size_t)l * DCN_D)[t];
        cur.x = fmaf(x0.x, s, b.x + cur.x);
        cur.y = fmaf(x0.y, s, b.y + cur.y);
        cur.z = fmaf(x0.z, s, b.z + cur.z);
        cur.w = fmaf(x0.w, s, b.w + cur.w);
        __syncthreads();  // red[] reused next layer
    }

    reinterpret_cast<float4*>(out + (size_t)row * DCN_D)[t] = cur;
}

extern "C" void kernel_launch(void* const* d_in, const int* in_sizes, int n_in,
                              void* d_out, int out_size, void* d_ws, size_t ws_size,
                              hipStream_t stream) {
    const float* x = (const float*)d_in[0];
    const float* w = (const float*)d_in[1];
    const float* b = (const float*)d_in[2];
    float* out = (float*)d_out;
    const int B = in_sizes[0] / DCN_D;

    dcn_cross_kernel<<<B, DCN_BLOCK, 0, stream>>>(x, w, b, out, B);
}

// Round 2
// 51.378 us; speedup vs baseline: 1.1842x; 1.1842x over previous
//
#include <hip/hip_runtime.h>

// DCN cross net, algebraically unrolled:
//   d_l = x0.w_l  (4 independent dots per row)
//   s_0=d_0; s_1=d_1(1+s_0)+c01; s_2=d_2(1+s0+s1)+c02+c12; s_3=d_3(1+s0+s1+s2)+c03+c13+c23
//   out = x0*(1+Σs_l) + Σb_l
// c_{jl}=b_j.w_l and Bsum=Σb_l precomputed into ws by a tiny kernel.
// Main kernel: one row per wave (64 lanes x 16 elems), no LDS, no barriers.

#define DCN_D 1024
#define DCN_F4 (DCN_D / 4)   // 256 float4 per row

// ws layout: ws[0..1023] = Bsum; ws[1024..1029] = {c01,c02,c12,c03,c13,c23}

__global__ __launch_bounds__(256) void dcn_pre_kernel(
    const float* __restrict__ w,   // [4, D]
    const float* __restrict__ b,   // [4, D]
    float* __restrict__ ws)
{
    const int t = threadIdx.x;
    // Bsum
    for (int d = t; d < DCN_D; d += 256)
        ws[d] = b[d] + b[DCN_D + d] + b[2 * DCN_D + d] + b[3 * DCN_D + d];
    // six dots b_j . w_l (j < l)
    float p[6] = {0, 0, 0, 0, 0, 0};
    for (int d = t; d < DCN_D; d += 256) {
        const float b0 = b[d], b1 = b[DCN_D + d], b2 = b[2 * DCN_D + d];
        const float w1 = w[DCN_D + d], w2 = w[2 * DCN_D + d], w3 = w[3 * DCN_D + d];
        p[0] = fmaf(b0, w1, p[0]);
        p[1] = fmaf(b0, w2, p[1]);
        p[2] = fmaf(b1, w2, p[2]);
        p[3] = fmaf(b0, w3, p[3]);
        p[4] = fmaf(b1, w3, p[4]);
        p[5] = fmaf(b2, w3, p[5]);
    }
    __shared__ float red[6][4];
    const int wave = t >> 6, lane = t & 63;
    #pragma unroll
    for (int k = 0; k < 6; ++k) {
        float v = p[k];
        #pragma unroll
        for (int off = 32; off > 0; off >>= 1) v += __shfl_down(v, off, 64);
        if (lane == 0) red[k][wave] = v;
    }
    __syncthreads();
    if (t < 6) ws[DCN_D + t] = red[t][0] + red[t][1] + red[t][2] + red[t][3];
}

__global__ __launch_bounds__(256) void dcn_main_kernel(
    const float* __restrict__ x,
    const float* __restrict__ w,
    const float* __restrict__ ws,
    float* __restrict__ out,
    int B)
{
    const int row  = (int)((blockIdx.x * 256u + threadIdx.x) >> 6);  // one wave per row
    const int lane = threadIdx.x & 63;
    if (row >= B) return;

    const float4* __restrict__ xr = reinterpret_cast<const float4*>(x + (size_t)row * DCN_D);
    const float4* __restrict__ w4 = reinterpret_cast<const float4*>(w);

    float4 xv[4];
    float p0 = 0.f, p1 = 0.f, p2 = 0.f, p3 = 0.f;

    #pragma unroll
    for (int j = 0; j < 4; ++j) {
        const int idx = lane + 64 * j;
        const float4 xc = xr[idx];
        xv[j] = xc;
        const float4 w0 = w4[idx];
        const float4 w1 = w4[DCN_F4 + idx];
        const float4 w2 = w4[2 * DCN_F4 + idx];
        const float4 w3 = w4[3 * DCN_F4 + idx];
        p0 = fmaf(xc.x, w0.x, fmaf(xc.y, w0.y, fmaf(xc.z, w0.z, fmaf(xc.w, w0.w, p0))));
        p1 = fmaf(xc.x, w1.x, fmaf(xc.y, w1.y, fmaf(xc.z, w1.z, fmaf(xc.w, w1.w, p1))));
        p2 = fmaf(xc.x, w2.x, fmaf(xc.y, w2.y, fmaf(xc.z, w2.z, fmaf(xc.w, w2.w, p2))));
        p3 = fmaf(xc.x, w3.x, fmaf(xc.y, w3.y, fmaf(xc.z, w3.z, fmaf(xc.w, w3.w, p3))));
    }

    // butterfly reduce all four dots (independent -> pipelined)
    #pragma unroll
    for (int off = 1; off < 64; off <<= 1) {
        p0 += __shfl_xor(p0, off, 64);
        p1 += __shfl_xor(p1, off, 64);
        p2 += __shfl_xor(p2, off, 64);
        p3 += __shfl_xor(p3, off, 64);
    }

    // scalar recurrence
    const float c01 = ws[DCN_D + 0], c02 = ws[DCN_D + 1], c12 = ws[DCN_D + 2];
    const float c03 = ws[DCN_D + 3], c13 = ws[DCN_D + 4], c23 = ws[DCN_D + 5];
    const float s0 = p0;
    const float t1 = 1.f + s0;
    const float s1 = fmaf(p1, t1, c01);
    const float t2 = t1 + s1;
    const float s2 = fmaf(p2, t2, c02 + c12);
    const float t3 = t2 + s2;
    const float s3 = fmaf(p3, t3, c03 + c13 + c23);
    const float S  = t3 + s3;

    const float4* __restrict__ bs4 = reinterpret_cast<const float4*>(ws);
    float4* __restrict__ o4 = reinterpret_cast<float4*>(out + (size_t)row * DCN_D);
    #pragma unroll
    for (int j = 0; j < 4; ++j) {
        const int idx = lane + 64 * j;
        const float4 bb = bs4[idx];
        float4 o;
        o.x = fmaf(xv[j].x, S, bb.x);
        o.y = fmaf(xv[j].y, S, bb.y);
        o.z = fmaf(xv[j].z, S, bb.z);
        o.w = fmaf(xv[j].w, S, bb.w);
        o4[idx] = o;
    }
}

extern "C" void kernel_launch(void* const* d_in, const int* in_sizes, int n_in,
                              void* d_out, int out_size, void* d_ws, size_t ws_size,
                              hipStream_t stream) {
    const float* x = (const float*)d_in[0];
    const float* w = (const float*)d_in[1];
    const float* b = (const float*)d_in[2];
    float* out = (float*)d_out;
    float* ws = (float*)d_ws;
    const int B = in_sizes[0] / DCN_D;

    dcn_pre_kernel<<<1, 256, 0, stream>>>(w, b, ws);
    const int rows_per_block = 4;  // 256 threads = 4 waves = 4 rows
    dcn_main_kernel<<<(B + rows_per_block - 1) / rows_per_block, 256, 0, stream>>>(
        x, w, ws, out, B);
}

// Round 5
// 50.018 us; speedup vs baseline: 1.2164x; 1.0272x over previous
//
#include <hip/hip_runtime.h>

// DCN cross net, algebraically unrolled (see round 1). This round:
//  - 2 rows per wave: 2x MLP on the HBM x-loads, w/bias fragments reused
//    across both rows (halves L1 instruction traffic per row)
//  - REGULAR stores for out (nt stores broke coherence vs the harness's
//    kernel-based poison fill: dirty 0xAA L2 lines wrote back over nt data)
//  - no LDS, no barriers in main kernel

#define DCN_D 1024
#define DCN_F4 (DCN_D / 4)   // 256 float4 per row

// ws layout: ws[0..1023] = Bsum; ws[1024..1029] = {c01,c02,c12,c03,c13,c23}

__global__ __launch_bounds__(256) void dcn_pre_kernel(
    const float* __restrict__ w,   // [4, D]
    const float* __restrict__ b,   // [4, D]
    float* __restrict__ ws)
{
    const int t = threadIdx.x;
    for (int d = t; d < DCN_D; d += 256)
        ws[d] = b[d] + b[DCN_D + d] + b[2 * DCN_D + d] + b[3 * DCN_D + d];
    float p[6] = {0, 0, 0, 0, 0, 0};
    for (int d = t; d < DCN_D; d += 256) {
        const float b0 = b[d], b1 = b[DCN_D + d], b2 = b[2 * DCN_D + d];
        const float w1 = w[DCN_D + d], w2 = w[2 * DCN_D + d], w3 = w[3 * DCN_D + d];
        p[0] = fmaf(b0, w1, p[0]);
        p[1] = fmaf(b0, w2, p[1]);
        p[2] = fmaf(b1, w2, p[2]);
        p[3] = fmaf(b0, w3, p[3]);
        p[4] = fmaf(b1, w3, p[4]);
        p[5] = fmaf(b2, w3, p[5]);
    }
    __shared__ float red[6][4];
    const int wave = t >> 6, lane = t & 63;
    #pragma unroll
    for (int k = 0; k < 6; ++k) {
        float v = p[k];
        #pragma unroll
        for (int off = 32; off > 0; off >>= 1) v += __shfl_down(v, off, 64);
        if (lane == 0) red[k][wave] = v;
    }
    __syncthreads();
    if (t < 6) ws[DCN_D + t] = red[t][0] + red[t][1] + red[t][2] + red[t][3];
}

__device__ __forceinline__ float dcn_scalar_S(const float p[4], const float* cw) {
    const float c01 = cw[0], c02 = cw[1], c12 = cw[2];
    const float c03 = cw[3], c13 = cw[4], c23 = cw[5];
    const float s0 = p[0];
    const float t1 = 1.f + s0;
    const float s1 = fmaf(p[1], t1, c01);
    const float t2 = t1 + s1;
    const float s2 = fmaf(p[2], t2, c02 + c12);
    const float t3 = t2 + s2;
    const float s3 = fmaf(p[3], t3, c03 + c13 + c23);
    return t3 + s3;
}

__global__ __launch_bounds__(256) void dcn_main_kernel(
    const float* __restrict__ x,
    const float* __restrict__ w,
    const float* __restrict__ ws,
    float* __restrict__ out,
    int B)
{
    const int wgid = (int)((blockIdx.x * 256u + threadIdx.x) >> 6);  // global wave id
    const int lane = threadIdx.x & 63;
    const int row0 = wgid * 2;
    if (row0 >= B) return;
    const bool has2 = (row0 + 1) < B;
    const int row1 = has2 ? row0 + 1 : row0;

    const float4* __restrict__ xr0 = reinterpret_cast<const float4*>(x + (size_t)row0 * DCN_D);
    const float4* __restrict__ xr1 = reinterpret_cast<const float4*>(x + (size_t)row1 * DCN_D);
    const float4* __restrict__ w4  = reinterpret_cast<const float4*>(w);

    // issue all x loads up-front (8 outstanding HBM loads)
    float4 xv0[4], xv1[4];
    #pragma unroll
    for (int j = 0; j < 4; ++j) xv0[j] = xr0[lane + 64 * j];
    #pragma unroll
    for (int j = 0; j < 4; ++j) xv1[j] = xr1[lane + 64 * j];

    float p0[4] = {0, 0, 0, 0}, p1[4] = {0, 0, 0, 0};
    #pragma unroll
    for (int j = 0; j < 4; ++j) {
        const int idx = lane + 64 * j;
        #pragma unroll
        for (int l = 0; l < 4; ++l) {
            const float4 wv = w4[l * DCN_F4 + idx];   // L1-resident, shared by both rows
            p0[l] = fmaf(xv0[j].x, wv.x, fmaf(xv0[j].y, wv.y,
                    fmaf(xv0[j].z, wv.z, fmaf(xv0[j].w, wv.w, p0[l]))));
            p1[l] = fmaf(xv1[j].x, wv.x, fmaf(xv1[j].y, wv.y,
                    fmaf(xv1[j].z, wv.z, fmaf(xv1[j].w, wv.w, p1[l]))));
        }
    }

    // 8 independent butterfly reductions, pipelined
    #pragma unroll
    for (int off = 1; off < 64; off <<= 1) {
        #pragma unroll
        for (int l = 0; l < 4; ++l) {
            p0[l] += __shfl_xor(p0[l], off, 64);
            p1[l] += __shfl_xor(p1[l], off, 64);
        }
    }

    const float* cw = ws + DCN_D;
    const float S0 = dcn_scalar_S(p0, cw);
    const float S1 = dcn_scalar_S(p1, cw);

    const float4* __restrict__ bs4 = reinterpret_cast<const float4*>(ws);
    float4* __restrict__ o0 = reinterpret_cast<float4*>(out + (size_t)row0 * DCN_D);
    float4* __restrict__ o1 = reinterpret_cast<float4*>(out + (size_t)row1 * DCN_D);
    #pragma unroll
    for (int j = 0; j < 4; ++j) {
        const int idx = lane + 64 * j;
        const float4 bb = bs4[idx];               // L1-resident
        float4 a;
        a.x = fmaf(xv0[j].x, S0, bb.x);
        a.y = fmaf(xv0[j].y, S0, bb.y);
        a.z = fmaf(xv0[j].z, S0, bb.z);
        a.w = fmaf(xv0[j].w, S0, bb.w);
        o0[idx] = a;
        if (has2) {
            float4 c;
            c.x = fmaf(xv1[j].x, S1, bb.x);
            c.y = fmaf(xv1[j].y, S1, bb.y);
            c.z = fmaf(xv1[j].z, S1, bb.z);
            c.w = fmaf(xv1[j].w, S1, bb.w);
            o1[idx] = c;
        }
    }
}

extern "C" void kernel_launch(void* const* d_in, const int* in_sizes, int n_in,
                              void* d_out, int out_size, void* d_ws, size_t ws_size,
                              hipStream_t stream) {
    const float* x = (const float*)d_in[0];
    const float* w = (const float*)d_in[1];
    const float* b = (const float*)d_in[2];
    float* out = (float*)d_out;
    float* ws = (float*)d_ws;
    const int B = in_sizes[0] / DCN_D;

    dcn_pre_kernel<<<1, 256, 0, stream>>>(w, b, ws);
    // 2 rows per wave, 4 waves per block -> 8 rows per block
    const int rows_per_block = 8;
    dcn_main_kernel<<<(B + rows_per_block - 1) / rows_per_block, 256, 0, stream>>>(
        x, w, ws, out, B);
}